// Round 5
// baseline (453.216 us; speedup 1.0000x reference)
//
#include <hip/hip_runtime.h>
#include <hip/hip_bf16.h>

// Problem constants
constexpr int B_   = 32;
constexpr int CIN  = 64;
constexpr int HIN  = 128;
constexpr int WIN  = 128;
constexpr int COUT = 128;
constexpr int HO   = 126;
constexpr int WO   = 126;
constexpr int HP   = 63;
constexpr int WP   = 63;
constexpr int NG   = 8;
constexpr float EPS = 1e-5f;

typedef _Float16 f16x8 __attribute__((ext_vector_type(8)));
typedef _Float16 f16x2 __attribute__((ext_vector_type(2)));
typedef float    f32x16 __attribute__((ext_vector_type(16)));

// ws layout (bytes):
//   stats @ 0        : 512 floats (pad to 4096)
//   Wh    @ 4096     : 9*8*128*8 f16 = 147456 (chunk-arranged)     (ends 151552)
//   xh    @ 151552   : 32*128*128*64 f16 = 64 MB (px-XOR-swizzled) (ends 67260416; +4KB slack)
//   yp    @ 67264512 : 32*128*63*64 f16 = 33 MB (padded wp-stride 64)

// ---------- Prep: W (OIHW fp32) -> Wh[kk][t*2+q][co][8] f16 ----------
// Per-fragment B loads become single global_load_dwordx4 with lane-consecutive addresses
// (L1-broadcast across all waves on the CU).
__global__ __launch_bounds__(256)
void whprep_kernel(const float* __restrict__ W, _Float16* __restrict__ Wh)
{
    int i = blockIdx.x * 256 + threadIdx.x;      // 9*8*128*8 = 73728
    if (i >= 9 * 8 * COUT * 8) return;
    const int e  = i & 7;
    const int co = (i >> 3) & 127;
    const int tq = (i >> 10) & 7;
    const int kk = i >> 13;
    const int q  = tq & 1;
    const int t  = tq >> 1;
    const int ci = t * 16 + q * 8 + e;
    Wh[i] = (_Float16)W[((size_t)co * CIN + ci) * 9 + kk];
}

// ---------- Prep: x fp32 NCHW -> xh f16 NHWC, px-XOR-swizzled ----------
// Row elem layout: px*64 + ((8-elem chunk) ^ ((px&7)<<3)).  A linear copy of a row slice
// into LDS gives conflict-free (uniform 8-lanes-per-16B-slot) swizzled ds_read_b128.
__global__ __launch_bounds__(256)
void xprep_kernel(const float* __restrict__ x, _Float16* __restrict__ xh)
{
    const int tid = threadIdx.x;
    const int w = tid & 127;
    const int h = blockIdx.x * 2 + (tid >> 7);
    const int b = blockIdx.y;
    const float* xp = x + ((size_t)b * CIN * HIN + h) * WIN + w;   // + c*16384
    _Float16* opr = xh + ((size_t)(b * 128 + h)) * 8192;
    const int sw = (w & 7) << 3;
    #pragma unroll
    for (int cg = 0; cg < 8; ++cg) {
        f16x8 o;
        #pragma unroll
        for (int j = 0; j < 8; ++j)
            o[j] = (_Float16)xp[(size_t)(cg * 8 + j) * (HIN * WIN)];
        *(f16x8*)(opr + w * 64 + ((cg * 8) ^ sw)) = o;
    }
}

// ---------- Conv (implicit GEMM, 32x32x16 MFMA): A from LDS, B from global/L1 ----------
// grid (63 row-pairs, 2 px-halves, 32 batch); block 256 = 4 waves (mi row x ni cout-half).
// Wave tile: M=64 px x N=64 cout = 2x2 of 32x32; acc = 64 AGPR -> ~190 unified regs of
// headroom under the (256,2) cap for the compiler to pipeline B loads across taps.
// A staged ONCE in prologue (4 rows x 66 px, 33.8 KB); ZERO barriers inside the K-loop
// (no vmcnt(0) drains); 9 taps fully unrolled.
__global__ __launch_bounds__(256, 2)
void conv_mfma_kernel(const _Float16* __restrict__ xh, const _Float16* __restrict__ Wh,
                      const float* __restrict__ bias, const float* __restrict__ gamma,
                      const float* __restrict__ scale,
                      _Float16* __restrict__ yp, float* __restrict__ stats)
{
    const int tid  = threadIdx.x;
    const int lane = tid & 63;
    const int wave = tid >> 6;
    const int mi   = wave & 1;       // output row 2rp+mi
    const int ni   = wave >> 1;      // cout half (0: 0..63, 1: 64..127)
    const int cl   = lane & 31;      // m-lane (px) for A, n-lane (cout) for B/D
    const int q    = lane >> 5;      // k-half
    const int rp   = blockIdx.x;     // 0..62
    const int half = blockIdx.y;     // px half (0: 0..63, 1: 64..127)
    const int b    = blockIdx.z;

    // [4 input rows][66 px][64 elems] f16, row stride 4224 elems = 8448 B; total 33792 B.
    __shared__ __align__(16) _Float16 sx[4 * 4224];

    // ---- stage 4 rows x 66 px (linear copy of pre-swizzled row slices) ----
    {
        const size_t base = ((size_t)(b * 128 + 2 * rp)) * 8192 + (size_t)half * 64 * 64;
        #pragma unroll
        for (int i = 0; i < 9; ++i) {
            const int idx = i * 256 + tid;         // chunk-of-8 index, 0..2111
            if (idx < 2112) {
                const int row = idx / 528;         // 528 chunks per row (66 px * 8)
                const int c8  = idx - row * 528;
                // px 128/129 over-read past row end: next row / xh slack, feeds only wo>=126
                const f16x8 v = *(const f16x8*)(xh + base + (size_t)row * 8192 + c8 * 8);
                *(f16x8*)(sx + row * 4224 + c8 * 8) = v;
            }
        }
    }
    __syncthreads();

    f32x16 acc[2][2] = {};   // [mt][nt]

    const _Float16* bp = Wh + q * 1024 + (ni * 64 + cl) * 8;  // + kk*8192 + t*2048 + nt*256

    #pragma unroll
    for (int kk = 0; kk < 9; ++kk) {
        const int kh = kk / 3, kw = kk - kh * 3;
        const _Float16* bt = bp + kk * 8192;
        const int swl = ((cl + kw) & 7) << 3;
        const _Float16* at = sx + (mi + kh) * 4224 + (cl + kw) * 64;   // + mt*2048 + col
        f16x8 bf[4][2], af[4][2];
        #pragma unroll
        for (int t = 0; t < 4; ++t) {
            bf[t][0] = *(const f16x8*)(bt + t * 2048);
            bf[t][1] = *(const f16x8*)(bt + t * 2048 + 256);
        }
        #pragma unroll
        for (int t = 0; t < 4; ++t) {
            const int col = (q * 8 + t * 16) ^ swl;
            af[t][0] = *(const f16x8*)(at + col);
            af[t][1] = *(const f16x8*)(at + 2048 + col);
        }
        #pragma unroll
        for (int t = 0; t < 4; ++t) {
            acc[0][0] = __builtin_amdgcn_mfma_f32_32x32x16_f16(af[t][0], bf[t][0], acc[0][0], 0, 0, 0);
            acc[0][1] = __builtin_amdgcn_mfma_f32_32x32x16_f16(af[t][0], bf[t][1], acc[0][1], 0, 0, 0);
            acc[1][0] = __builtin_amdgcn_mfma_f32_32x32x16_f16(af[t][1], bf[t][0], acc[1][0], 0, 0, 0);
            acc[1][1] = __builtin_amdgcn_mfma_f32_32x32x16_f16(af[t][1], bf[t][1], acc[1][1], 0, 0, 0);
        }
    }

    // ---- epilogue: bias, stats, horizontal pool ----
    // D layout (32x32): col(cout)=cl, row(px in tile) = (r&3)+4q+8(r>>2); r = ru*4+pl*2+e.
    // wo = half*64 + mt*32 + 8ru + 4q + 2pl + e; invalid only wo>=126 (half=1,mt=1,ru=3,q=1,pl=1).
    float ev[2][2][4][2];   // [nt][mt][ru][pl] horizontal extremum
    float s1[2] = {0.f, 0.f}, s2[2] = {0.f, 0.f};
    bool  useMin[2];
    #pragma unroll
    for (int nt = 0; nt < 2; ++nt) {
        const int co = ni * 64 + nt * 32 + cl;
        const float bv = bias[co];
        useMin[nt] = (gamma[co] * scale[co]) < 0.0f;   // affine slope sign (rstd>0)
        #pragma unroll
        for (int mt = 0; mt < 2; ++mt)
            #pragma unroll
            for (int ru = 0; ru < 4; ++ru)
                #pragma unroll
                for (int pl = 0; pl < 2; ++pl) {
                    const float e0 = acc[mt][nt][ru * 4 + pl * 2 + 0] + bv;
                    const float e1 = acc[mt][nt][ru * 4 + pl * 2 + 1] + bv;
                    const bool bad = (half == 1) && (mt == 1) && (ru == 3) && (q == 1) && (pl == 1);
                    if (!bad) { s1[nt] += e0 + e1; s2[nt] += e0 * e0 + e1 * e1; }
                    ev[nt][mt][ru][pl] = useMin[nt] ? fminf(e0, e1) : fmaxf(e0, e1);
                }
    }

    // stats: reduce over the 32 lanes sharing a 16-cout group-half: xor 1,2,4,8,32
    #pragma unroll
    for (int nt = 0; nt < 2; ++nt) {
        float a1 = s1[nt], a2 = s2[nt];
        a1 += __shfl_xor(a1, 1);  a2 += __shfl_xor(a2, 1);
        a1 += __shfl_xor(a1, 2);  a2 += __shfl_xor(a2, 2);
        a1 += __shfl_xor(a1, 4);  a2 += __shfl_xor(a2, 4);
        a1 += __shfl_xor(a1, 8);  a2 += __shfl_xor(a2, 8);
        a1 += __shfl_xor(a1, 32); a2 += __shfl_xor(a2, 32);
        if ((lane & 15) == 0 && lane < 32) {
            const int g = ni * 4 + nt * 2 + (cl >> 4);
            atomicAdd(&stats[((size_t)b * NG + g) * 2 + 0], a1);
            atomicAdd(&stats[((size_t)b * NG + g) * 2 + 1], a2);
        }
    }

    // vertical combine: mi=1 publishes, mi=0 combines + stores yp
    __syncthreads();               // all K-loop LDS reads done; safe to reuse sx
    _Float16* ex = sx;             // [ (ni*2+nt)*32 + pp ][ cl ] f16, 8KB
    if (mi == 1) {
        #pragma unroll
        for (int nt = 0; nt < 2; ++nt)
            #pragma unroll
            for (int mt = 0; mt < 2; ++mt)
                #pragma unroll
                for (int ru = 0; ru < 4; ++ru)
                    #pragma unroll
                    for (int pl = 0; pl < 2; ++pl) {
                        const int pp = mt * 16 + ru * 4 + q * 2 + pl;
                        ex[((ni * 2 + nt) * 32 + pp) * 32 + cl] = (_Float16)ev[nt][mt][ru][pl];
                    }
    }
    __syncthreads();
    if (mi == 0) {
        #pragma unroll
        for (int nt = 0; nt < 2; ++nt) {
            const int co = ni * 64 + nt * 32 + cl;
            _Float16* ypp = yp + ((size_t)(b * COUT + co) * HP + rp) * 64 + half * 32;
            #pragma unroll
            for (int mt = 0; mt < 2; ++mt)
                #pragma unroll
                for (int ru = 0; ru < 4; ++ru) {
                    const int ppb = mt * 16 + ru * 4 + q * 2;
                    const float r0 = (float)ex[((ni * 2 + nt) * 32 + ppb + 0) * 32 + cl];
                    const float r1 = (float)ex[((ni * 2 + nt) * 32 + ppb + 1) * 32 + cl];
                    const float c0 = useMin[nt] ? fminf(ev[nt][mt][ru][0], r0) : fmaxf(ev[nt][mt][ru][0], r0);
                    const float c1 = useMin[nt] ? fminf(ev[nt][mt][ru][1], r1) : fmaxf(ev[nt][mt][ru][1], r1);
                    *(f16x2*)(ypp + ppb) = (f16x2){(_Float16)c0, (_Float16)c1};
                }
        }
    }
}

// ---------- GroupNorm affine + clamp on pre-pooled extrema ----------
// One block per (b,c) plane: coefficients once per block, f16x2-vectorized stream.
__global__ __launch_bounds__(256)
void gn_pool_kernel(const _Float16* __restrict__ yp, const float* __restrict__ stats,
                    const float* __restrict__ gamma, const float* __restrict__ beta,
                    const float* __restrict__ scale, float* __restrict__ out)
{
    const int bc = blockIdx.x;           // b*COUT + c
    const int c  = bc & 127;
    const int b  = bc >> 7;
    const int g  = c >> 4;

    const float s1 = stats[((size_t)b * NG + g) * 2 + 0];
    const float s2 = stats[((size_t)b * NG + g) * 2 + 1];
    constexpr float inv = 1.0f / (float)((COUT / NG) * HO * WO);
    const float mean = s1 * inv;
    const float var  = fmaf(-mean, mean, s2 * inv);
    const float rstd = rsqrtf(var + EPS);
    const float sc   = scale[c];
    const float a    = rstd * gamma[c] * sc;
    const float bb   = fmaf(-mean, rstd * gamma[c], beta[c]) * sc;

    const _Float16* ypp = yp + (size_t)bc * HP * 64;
    float* op = out + (size_t)bc * HP * WP;
    #pragma unroll
    for (int it = 0; it < 8; ++it) {
        const int j = it * 256 + threadIdx.x;     // pair index, 63 rows x 32 pairs = 2016
        if (j < 2016) {
            const int wp = (j & 31) * 2;
            const int hp = j >> 5;
            const f16x2 v = *(const f16x2*)(ypp + hp * 64 + wp);
            float m0 = fmaf((float)v[0], a, bb);
            m0 = fminf(fmaxf(m0, 0.0f), 1.0f);
            op[hp * WP + wp] = m0;
            if (wp + 1 < WP) {
                float m1 = fmaf((float)v[1], a, bb);
                m1 = fminf(fmaxf(m1, 0.0f), 1.0f);
                op[hp * WP + wp + 1] = m1;
            }
        }
    }
}

extern "C" void kernel_launch(void* const* d_in, const int* in_sizes, int n_in,
                              void* d_out, int out_size, void* d_ws, size_t ws_size,
                              hipStream_t stream)
{
    const float* x     = (const float*)d_in[0];
    const float* W     = (const float*)d_in[1];
    const float* bias  = (const float*)d_in[2];
    const float* scale = (const float*)d_in[3];
    const float* gamma = (const float*)d_in[4];
    const float* beta  = (const float*)d_in[5];

    float*    stats = (float*)d_ws;
    _Float16* Wh    = (_Float16*)((char*)d_ws + 4096);
    _Float16* xh    = (_Float16*)((char*)d_ws + 151552);
    _Float16* yp    = (_Float16*)((char*)d_ws + 67264512);
    float*    out   = (float*)d_out;

    hipMemsetAsync(stats, 0, B_ * NG * 2 * sizeof(float), stream);

    whprep_kernel<<<(9 * 8 * COUT * 8 + 255) / 256, 256, 0, stream>>>(W, Wh);
    xprep_kernel<<<dim3(64, B_), 256, 0, stream>>>(x, xh);
    conv_mfma_kernel<<<dim3(63, 2, B_), 256, 0, stream>>>(xh, Wh, bias, gamma, scale, yp, stats);
    gn_pool_kernel<<<B_ * COUT, 256, 0, stream>>>(yp, stats, gamma, beta, scale, out);
}